// Round 13
// baseline (759.973 us; speedup 1.0000x reference)
//
#include <hip/hip_runtime.h>
#include <hip/hip_cooperative_groups.h>
#include <hip/hip_bf16.h>

namespace cg = cooperative_groups;

#define N_NODES 10000
#define N_EDGES 320000
#define IN_CH 128
#define HID 64
#define HEADS 8
#define OUT_CH 2
#define BM 64
#define BK 16

__device__ __forceinline__ unsigned short f2bf(float f) {
    union { float f; unsigned u; } v; v.f = f;
    unsigned r = (v.u + 0x7FFFu + ((v.u >> 16) & 1u)) >> 16;  // RNE
    return (unsigned short)r;
}

// ---------------------------------------------------------------------------
// Single cooperative kernel: 9 phases, 8 grid syncs.
//  A: zero counts + GEMM1 (64x64 tile, f4-staged, prefetch) + es/ed epilogue
//  B: count edges   C: chunk scan   D: scan finalize   E: fill CSR
//  F: layer-1 aggregation (head-pair, bf16, bpermute broadcast)
//  G: GEMM2 split-K by head   H: reduce partials + es2/ed2   I: agg2+classifier
// ---------------------------------------------------------------------------
__global__ __launch_bounds__(256, 4) void fused_all(
    const float* __restrict__ x,
    const int* __restrict__ esrc, const int* __restrict__ edst,
    const float* __restrict__ W1, const float* __restrict__ a_src1,
    const float* __restrict__ a_dst1, const float* __restrict__ b1,
    const float* __restrict__ W2, const float* __restrict__ a_src2,
    const float* __restrict__ a_dst2, const float* __restrict__ b2,
    const float* __restrict__ Wc, const float* __restrict__ bc,
    int* counts, int* offsets, int* cursor, int* csr_src,
    int* temp, int* blocktot,
    unsigned short* hfeatP, float* esAll, float* edAll, float* h1,
    float* partial, float* hfeat2, float* es2, float* ed2,
    float* out) {
    cg::grid_group grid = cg::this_grid();
    const int tid = threadIdx.x;
    const int nb = gridDim.x;
    const int gsize = nb * 256;
    const int gtid = blockIdx.x * 256 + tid;
    const int M = N_NODES;

    __shared__ float As[BK][BM + 1];
    __shared__ float Bs[BK][64 + 1];
    __shared__ int wtot[4];
    __shared__ int preS;

    // ================= Phase A: zero counts + GEMM1 =================
    for (int i = gtid; i < N_NODES; i += gsize) counts[i] = 0;
    {
        int tx = tid & 15, ty = tid >> 4;
        int ar = tid >> 2, ac = (tid & 3) * 4;       // A staging: row, col-quad
        int br = tid >> 4, bc4 = (tid & 15) * 4;     // B staging: row, col-quad
        for (int vb = blockIdx.x; vb < 157 * 8; vb += nb) {
            int h = vb & 7;
            int bm = (vb >> 3) * BM;
            const float* Bw = W1 + h * 64;           // ldb = 512
            int agr = bm + ar;
            float4 av = (agr < M)
                ? *(const float4*)&x[(size_t)agr * IN_CH + ac]
                : make_float4(0.f, 0.f, 0.f, 0.f);
            float4 bv = *(const float4*)&Bw[(size_t)br * (HEADS * HID) + bc4];
            float acc[4][4] = {};
            for (int k0 = 0; k0 < IN_CH; k0 += BK) {
                As[ac + 0][ar] = av.x; As[ac + 1][ar] = av.y;
                As[ac + 2][ar] = av.z; As[ac + 3][ar] = av.w;
                *(float4*)&Bs[br][bc4] = bv;
                __syncthreads();
                if (k0 + BK < IN_CH) {
                    av = (agr < M)
                        ? *(const float4*)&x[(size_t)agr * IN_CH + (k0 + BK) + ac]
                        : make_float4(0.f, 0.f, 0.f, 0.f);
                    bv = *(const float4*)&Bw[(size_t)(k0 + BK + br) * (HEADS * HID) + bc4];
                }
                #pragma unroll
                for (int k = 0; k < BK; k++) {
                    float a[4], b[4];
                    #pragma unroll
                    for (int i2 = 0; i2 < 4; i2++) a[i2] = As[k][ty * 4 + i2];
                    #pragma unroll
                    for (int j = 0; j < 4; j++) b[j] = Bs[k][tx * 4 + j];
                    #pragma unroll
                    for (int i2 = 0; i2 < 4; i2++)
                        #pragma unroll
                        for (int j = 0; j < 4; j++) acc[i2][j] += a[i2] * b[j];
                }
                __syncthreads();
            }
            float asv[4], adv[4];
            #pragma unroll
            for (int j = 0; j < 4; j++) {
                asv[j] = a_src1[h * 64 + tx * 4 + j];
                adv[j] = a_dst1[h * 64 + tx * 4 + j];
            }
            int ph = h >> 1, hs = h & 1;
            #pragma unroll
            for (int i2 = 0; i2 < 4; i2++) {
                int gr = bm + ty * 4 + i2;
                if (gr < M) {
                    float sp = 0.f, dp = 0.f;
                    ushort4 pk;
                    pk.x = f2bf(acc[i2][0]); pk.y = f2bf(acc[i2][1]);
                    pk.z = f2bf(acc[i2][2]); pk.w = f2bf(acc[i2][3]);
                    *(ushort4*)&hfeatP[((size_t)ph * M + gr) * 128 + hs * 64 + tx * 4] = pk;
                    #pragma unroll
                    for (int j = 0; j < 4; j++) {
                        sp += acc[i2][j] * asv[j];
                        dp += acc[i2][j] * adv[j];
                    }
                    #pragma unroll
                    for (int off = 1; off < 16; off <<= 1) {
                        sp += __shfl_xor(sp, off, 64);
                        dp += __shfl_xor(dp, off, 64);
                    }
                    if (tx == 0) {
                        esAll[(size_t)h * M + gr] = sp;
                        edAll[(size_t)h * M + gr] = dp;
                    }
                } else {
                    // keep shuffles uniform even for OOB rows
                    float sp = 0.f, dp = 0.f;
                    #pragma unroll
                    for (int off = 1; off < 16; off <<= 1) {
                        sp += __shfl_xor(sp, off, 64);
                        dp += __shfl_xor(dp, off, 64);
                    }
                }
            }
        }
    }
    grid.sync();

    // ================= Phase B: count edges =================
    for (int i = gtid; i < N_EDGES; i += gsize) atomicAdd(&counts[edst[i]], 1);
    grid.sync();

    // ================= Phase C: per-chunk scan (40 chunks of 256) ==========
    for (int vb = blockIdx.x; vb < 40; vb += nb) {
        int i = vb * 256 + tid;
        int v = (i < N_NODES) ? counts[i] : 0;
        int lane = tid & 63, w = tid >> 6;
        int xv = v;
        #pragma unroll
        for (int off = 1; off < 64; off <<= 1) {
            int y = __shfl_up(xv, off, 64);
            if (lane >= off) xv += y;
        }
        if (lane == 63) wtot[w] = xv;
        __syncthreads();
        if (tid == 0) {
            int s = 0;
            #pragma unroll
            for (int j = 0; j < 4; j++) { int t = wtot[j]; wtot[j] = s; s += t; }
        }
        __syncthreads();
        int incl = xv + wtot[w];
        if (i < N_NODES) temp[i] = incl;
        if (tid == 255) blocktot[vb] = incl;
        __syncthreads();
    }
    grid.sync();

    // ================= Phase D: scan finalize =================
    for (int vb = blockIdx.x; vb < 40; vb += nb) {
        if (tid == 0) {
            int pre = 0;
            for (int j = 0; j < vb; j++) pre += blocktot[j];
            preS = pre;
        }
        __syncthreads();
        int i = vb * 256 + tid;
        if (i < N_NODES) {
            int incl = preS + temp[i];
            int excl = incl - counts[i];
            offsets[i] = excl;
            cursor[i] = excl;
            if (i == N_NODES - 1) offsets[N_NODES] = incl;
        }
        __syncthreads();
    }
    grid.sync();

    // ================= Phase E: fill CSR =================
    for (int i = gtid; i < N_EDGES; i += gsize) {
        int p2 = atomicAdd(&cursor[edst[i]], 1);
        csr_src[p2] = esrc[i];
    }
    grid.sync();

    // ================= Phase F: layer-1 aggregation (head pairs) ===========
    for (int vb = blockIdx.x; vb < N_NODES; vb += nb) {
        int p = vb & 3;
        int n = (vb >> 2) * 4 + (tid >> 6);
        int l = tid & 63;
        int g = l >> 4;
        int q = l & 15;
        int hq = q >> 3;
        int sub = l & 31;
        int hs = l >> 5;
        int g4 = g << 2;
        int hbaseB = hq << 7;
        const char* hptr = (const char*)hfeatP + (size_t)p * M * 256 + (q << 4);
        const float* esS = esAll + (size_t)(p * 2 + hs) * M;
        float ednS = edAll[(size_t)(p * 2 + hs) * M + n];
        int start = offsets[n];
        int deg = offsets[n + 1] - start;
        int total = deg + 1;

        float a[8] = {};
        float dloc = 0.f;
        for (int base = 0; base < total; base += 32) {
            int idx = base + sub;
            int sld = csr_src[start + idx];          // csr_src padded +32
            int sv = (idx < deg) ? sld : n;
            float wgt = 0.f;
            if (idx <= deg) {
                float e = esS[sv] + ednS;
                e = (e > 0.f) ? e : 0.2f * e;
                wgt = __expf(e);
            }
            dloc += wgt;
            int rb = sv << 8;
            int wb = __float_as_int(wgt);
            int cnt = min(32, total - base);
            for (int i = 0; i < cnt; i += 4) {
                int b0 = (i << 2) + g4;
                int rbg = __builtin_amdgcn_ds_bpermute(b0, rb);
                float wg = __int_as_float(
                    __builtin_amdgcn_ds_bpermute(b0 + hbaseB, wb));
                const uint4 hv = *(const uint4*)(hptr + rbg);
                a[0] += wg * __uint_as_float(hv.x << 16);
                a[1] += wg * __uint_as_float(hv.x & 0xFFFF0000u);
                a[2] += wg * __uint_as_float(hv.y << 16);
                a[3] += wg * __uint_as_float(hv.y & 0xFFFF0000u);
                a[4] += wg * __uint_as_float(hv.z << 16);
                a[5] += wg * __uint_as_float(hv.z & 0xFFFF0000u);
                a[6] += wg * __uint_as_float(hv.w << 16);
                a[7] += wg * __uint_as_float(hv.w & 0xFFFF0000u);
            }
        }
        #pragma unroll
        for (int off = 16; off; off >>= 1) dloc += __shfl_xor(dloc, off, 64);
        float dother = __shfl_xor(dloc, 32, 64);
        #pragma unroll
        for (int k = 0; k < 8; k++) {
            a[k] += __shfl_xor(a[k], 16, 64);
            a[k] += __shfl_xor(a[k], 32, 64);
        }
        if (g == 0) {
            float d = (hq == 0) ? dloc : dother;
            d += 1e-16f;
            float inv = __builtin_amdgcn_rcpf(d);
            inv = inv * __fmaf_rn(-d, inv, 2.0f);
            const float4 b0v = *(const float4*)&b1[p * 128 + q * 8];
            const float4 b4v = *(const float4*)&b1[p * 128 + q * 8 + 4];
            float vv[8];
            vv[0] = a[0] * inv + b0v.x; vv[1] = a[1] * inv + b0v.y;
            vv[2] = a[2] * inv + b0v.z; vv[3] = a[3] * inv + b0v.w;
            vv[4] = a[4] * inv + b4v.x; vv[5] = a[5] * inv + b4v.y;
            vv[6] = a[6] * inv + b4v.z; vv[7] = a[7] * inv + b4v.w;
            #pragma unroll
            for (int k = 0; k < 8; k++)
                vv[k] = (vv[k] > 0.f) ? vv[k] : (__expf(vv[k]) - 1.f);   // ELU
            float* dst = &h1[(size_t)n * 512 + p * 128 + q * 8];
            *(float4*)dst = make_float4(vv[0], vv[1], vv[2], vv[3]);
            *(float4*)(dst + 4) = make_float4(vv[4], vv[5], vv[6], vv[7]);
        }
    }
    grid.sync();

    // ================= Phase G: GEMM2 split-K by head =================
    {
        int tx = tid & 15, ty = tid >> 4;
        for (int vb = blockIdx.x; vb < 157 * 8; vb += nb) {
            int h = vb & 7;
            int bm = (vb >> 3) * BM;
            const float* Bw = W2 + (size_t)h * 64 * 64;
            float* C = partial + (size_t)h * M * 64;
            float acc[4][4] = {};
            for (int k0 = 0; k0 < 64; k0 += BK) {
                #pragma unroll
                for (int i = 0; i < 4; i++) {
                    int e = tid + i * 256;
                    int r = e >> 4, c = e & 15;
                    int gr = bm + r;
                    As[c][r] = (gr < M)
                        ? h1[(size_t)gr * 512 + h * 64 + k0 + c] : 0.f;
                }
                #pragma unroll
                for (int i = 0; i < 4; i++) {
                    int e = tid + i * 256;
                    int r = e >> 6, c = e & 63;
                    Bs[r][c] = Bw[(size_t)(k0 + r) * 64 + c];
                }
                __syncthreads();
                #pragma unroll
                for (int k = 0; k < BK; k++) {
                    float a[4], b[4];
                    #pragma unroll
                    for (int i = 0; i < 4; i++) a[i] = As[k][ty * 4 + i];
                    #pragma unroll
                    for (int j = 0; j < 4; j++) b[j] = Bs[k][tx * 4 + j];
                    #pragma unroll
                    for (int i = 0; i < 4; i++)
                        #pragma unroll
                        for (int j = 0; j < 4; j++) acc[i][j] += a[i] * b[j];
                }
                __syncthreads();
            }
            #pragma unroll
            for (int i = 0; i < 4; i++) {
                int gr = bm + ty * 4 + i;
                if (gr >= M) continue;
                #pragma unroll
                for (int j = 0; j < 4; j++)
                    C[(size_t)gr * 64 + tx * 4 + j] = acc[i][j];
            }
        }
    }
    grid.sync();

    // ================= Phase H: reduce partials + es2/ed2 =================
    for (int vb = blockIdx.x; vb < 2500; vb += nb) {
        int n = vb * 4 + (tid >> 6);
        int l = tid & 63;
        float v = 0.f;
        #pragma unroll
        for (int h = 0; h < 8; h++)
            v += partial[(size_t)h * M * 64 + (size_t)n * 64 + l];
        hfeat2[(size_t)n * 64 + l] = v;
        float s = v * a_src2[l], t = v * a_dst2[l];
        #pragma unroll
        for (int off = 32; off; off >>= 1) {
            s += __shfl_down(s, off, 64);
            t += __shfl_down(t, off, 64);
        }
        if (l == 0) { es2[n] = s; ed2[n] = t; }
    }
    grid.sync();

    // ================= Phase I: agg2 + classifier =================
    for (int vb = blockIdx.x; vb < 2500; vb += nb) {
        int n = vb * 4 + (tid >> 6);
        int l = tid & 63;
        int g = l >> 4;
        int q = l & 15;
        int g4 = g << 2;
        int qoff = q << 4;
        int start = offsets[n];
        int deg = offsets[n + 1] - start;
        int total = deg + 1;
        float edn = ed2[n];

        float ax = 0.f, ay = 0.f, az = 0.f, aw = 0.f;
        float dloc = 0.f;
        for (int base = 0; base < total; base += 64) {
            int cnt = min(64, total - base);
            float wgt = 0.f;
            int sv = n;
            if (l < cnt) {
                sv = (base + l < deg) ? csr_src[start + base + l] : n;
                float e = es2[sv] + edn;
                e = (e > 0.f) ? e : 0.2f * e;
                wgt = __expf(e);
            }
            dloc += wgt;
            int rb = sv << 8;
            int wb = __float_as_int(wgt);
            for (int i = 0; i < cnt; i += 4) {
                int bidx = (i << 2) + g4;
                int rbg = __builtin_amdgcn_ds_bpermute(bidx, rb);
                float wg = __int_as_float(__builtin_amdgcn_ds_bpermute(bidx, wb));
                const float4 hv = *(const float4*)((const char*)hfeat2 + (rbg + qoff));
                ax += wg * hv.x;
                ay += wg * hv.y;
                az += wg * hv.z;
                aw += wg * hv.w;
            }
        }
        float d = dloc;
        #pragma unroll
        for (int off = 32; off; off >>= 1) d += __shfl_down(d, off, 64);
        d = __shfl(d, 0, 64) + 1e-16f;
        float inv = __builtin_amdgcn_rcpf(d);
        inv = inv * __fmaf_rn(-d, inv, 2.0f);
        ax += __shfl_down(ax, 32, 64); ay += __shfl_down(ay, 32, 64);
        az += __shfl_down(az, 32, 64); aw += __shfl_down(aw, 32, 64);
        ax += __shfl_down(ax, 16, 64); ay += __shfl_down(ay, 16, 64);
        az += __shfl_down(az, 16, 64); aw += __shfl_down(aw, 16, 64);
        float p0 = 0.f, p1 = 0.f;
        if (g == 0) {
            const float4 bq = *(const float4*)&b2[q * 4];
            float h0 = ax * inv + bq.x, h1v = ay * inv + bq.y;
            float h2v = az * inv + bq.z, h3 = aw * inv + bq.w;
            const float2* WcV = (const float2*)Wc;
            float2 w0 = WcV[q * 4 + 0], w1 = WcV[q * 4 + 1];
            float2 w2 = WcV[q * 4 + 2], w3 = WcV[q * 4 + 3];
            p0 = h0 * w0.x + h1v * w1.x + h2v * w2.x + h3 * w3.x;
            p1 = h0 * w0.y + h1v * w1.y + h2v * w2.y + h3 * w3.y;
        }
        #pragma unroll
        for (int off = 1; off < 16; off <<= 1) {
            p0 += __shfl_xor(p0, off, 64);
            p1 += __shfl_xor(p1, off, 64);
        }
        if (l == 0) {
            out[n * 2 + 0] = p0 + bc[0];
            out[n * 2 + 1] = p1 + bc[1];
        }
    }
}

// ---------------------------------------------------------------------------
extern "C" void kernel_launch(void* const* d_in, const int* in_sizes, int n_in,
                              void* d_out, int out_size, void* d_ws, size_t ws_size,
                              hipStream_t stream) {
    const float* x      = (const float*)d_in[0];
    const int*   eidx   = (const int*)d_in[1];
    const float* W1     = (const float*)d_in[2];
    const float* a_src1 = (const float*)d_in[3];
    const float* a_dst1 = (const float*)d_in[4];
    const float* b1     = (const float*)d_in[5];
    const float* W2     = (const float*)d_in[6];
    const float* a_src2 = (const float*)d_in[7];
    const float* a_dst2 = (const float*)d_in[8];
    const float* b2     = (const float*)d_in[9];
    const float* Wc     = (const float*)d_in[10];
    const float* bc     = (const float*)d_in[11];
    float* out = (float*)d_out;

    const int N = N_NODES, E = N_EDGES;
    const int* esrc = eidx;
    const int* edst = eidx + E;

    // -------- workspace carve (256B aligned) --------
    size_t off = 0;
    auto alloc = [&](size_t bytes) {
        void* p = (char*)d_ws + off;
        off += (bytes + 255) & ~(size_t)255;
        return p;
    };
    int*   counts   = (int*)alloc((size_t)N * 4);
    int*   offsets  = (int*)alloc((size_t)(N + 1) * 4);
    int*   cursor   = (int*)alloc((size_t)N * 4);
    int*   csr_src  = (int*)alloc((size_t)(E + 32) * 4);
    int*   temp     = (int*)alloc((size_t)N * 4);
    int*   blocktot = (int*)alloc((size_t)64 * 4);
    unsigned short* hfeatP = (unsigned short*)alloc((size_t)4 * N * 128 * 2);
    float* h1       = (float*)alloc((size_t)N * 512 * 4);
    float* partial  = (float*)alloc((size_t)HEADS * N * 64 * 4);
    float* hfeat2   = (float*)alloc((size_t)N * 64 * 4);
    float* esAll    = (float*)alloc((size_t)HEADS * N * 4);
    float* edAll    = (float*)alloc((size_t)HEADS * N * 4);
    float* es2      = (float*)alloc((size_t)N * 4);
    float* ed2      = (float*)alloc((size_t)N * 4);

    // grid size: co-resident blocks only (cooperative launch requirement)
    int blocksPerCU = 0;
    hipOccupancyMaxActiveBlocksPerMultiprocessor(&blocksPerCU, fused_all, 256, 0);
    if (blocksPerCU < 1) blocksPerCU = 1;
    int nb = blocksPerCU * 256;          // 256 CUs on MI355X
    if (nb > 2048) nb = 2048;
    if (nb < 256) nb = 256;

    void* args[] = {
        (void*)&x, (void*)&esrc, (void*)&edst,
        (void*)&W1, (void*)&a_src1, (void*)&a_dst1, (void*)&b1,
        (void*)&W2, (void*)&a_src2, (void*)&a_dst2, (void*)&b2,
        (void*)&Wc, (void*)&bc,
        (void*)&counts, (void*)&offsets, (void*)&cursor, (void*)&csr_src,
        (void*)&temp, (void*)&blocktot,
        (void*)&hfeatP, (void*)&esAll, (void*)&edAll, (void*)&h1,
        (void*)&partial, (void*)&hfeat2, (void*)&es2, (void*)&ed2,
        (void*)&out
    };
    hipLaunchCooperativeKernel(fused_all, dim3(nb), dim3(256), args, 0, stream);
}

// Round 14
// 234.992 us; speedup vs baseline: 3.2340x; 3.2340x over previous
//
#include <hip/hip_runtime.h>
#include <hip/hip_bf16.h>

#define N_NODES 10000
#define N_EDGES 320000
#define IN_CH 128
#define HID 64
#define HEADS 8
#define OUT_CH 2
#define BM 64
#define BK 16

__device__ __forceinline__ unsigned short f2bf(float f) {
    union { float f; unsigned u; } v; v.f = f;
    unsigned r = (v.u + 0x7FFFu + ((v.u >> 16) & 1u)) >> 16;  // RNE
    return (unsigned short)r;
}

// ---------------------------------------------------------------------------
// CSR offsets in ONE kernel: single block, 40 KB LDS histogram.
//   zero hist (LDS) -> count 320k edges (int4 loads + LDS atomics) ->
//   wave-scan 10 chunks of 1024 -> offsets[0..N], cursor[0..N-1].
// Replaces zero_ints + count_edges + scan_block + scan_finalize (3 launches).
// ---------------------------------------------------------------------------
__global__ __launch_bounds__(1024) void build_csr_offsets(
    const int* __restrict__ dst, int* __restrict__ offsets,
    int* __restrict__ cursor) {
    __shared__ int hist[N_NODES];
    __shared__ int wtot[16];
    __shared__ int s_run;
    int tid = threadIdx.x;
    for (int i = tid; i < N_NODES; i += 1024) hist[i] = 0;
    if (tid == 0) s_run = 0;
    __syncthreads();
    const int4* d4 = (const int4*)dst;          // E % 4 == 0, 16B-aligned
    for (int i = tid; i < N_EDGES / 4; i += 1024) {
        int4 v = d4[i];
        atomicAdd(&hist[v.x], 1); atomicAdd(&hist[v.y], 1);
        atomicAdd(&hist[v.z], 1); atomicAdd(&hist[v.w], 1);
    }
    __syncthreads();
    int lane = tid & 63, w = tid >> 6;
    for (int base = 0; base < N_NODES; base += 1024) {
        int i = base + tid;
        int v = (i < N_NODES) ? hist[i] : 0;
        int x = v;
        #pragma unroll
        for (int off = 1; off < 64; off <<= 1) {
            int y = __shfl_up(x, off, 64);
            if (lane >= off) x += y;
        }
        if (lane == 63) wtot[w] = x;
        __syncthreads();
        if (w == 0) {
            int t = (lane < 16) ? wtot[lane] : 0;
            #pragma unroll
            for (int off = 1; off < 16; off <<= 1) {
                int y = __shfl_up(t, off, 64);
                if (lane >= off) t += y;
            }
            if (lane < 16) wtot[lane] = t;
        }
        __syncthreads();
        int waveoff = (w > 0) ? wtot[w - 1] : 0;
        int incl = x + waveoff + s_run;
        if (i < N_NODES) {
            offsets[i] = incl - v;
            cursor[i] = incl - v;
        }
        __syncthreads();
        if (tid == 1023) s_run = incl;
        __syncthreads();
    }
    if (tid == 0) offsets[N_NODES] = s_run;
}

__global__ void fill_csr(const int* __restrict__ src, const int* __restrict__ dst,
                         int E, int* cursor, int* __restrict__ csr_src) {
    int i = blockIdx.x * blockDim.x + threadIdx.x;
    if (i < E) {
        int p = atomicAdd(&cursor[dst[i]], 1);
        csr_src[p] = src[i];
    }
}

// ---------------------------------------------------------------------------
// GEMM1 per head (64x64 tile, 4x4 micro, grid 157x8), float4 staging +
// register prefetch. Output pair-blocked bf16 hfeatP[4][N][128]; fused es/ed.
// ---------------------------------------------------------------------------
__global__ __launch_bounds__(256) void gemm1_heads(
    const float* __restrict__ A,        // x [N, 128]
    const float* __restrict__ W1,       // [128, 512]
    const float* __restrict__ a_src1,   // [8, 64]
    const float* __restrict__ a_dst1,   // [8, 64]
    unsigned short* __restrict__ hfeatP,// [4][N][128] bf16
    float* __restrict__ esAll,          // [8][N]
    float* __restrict__ edAll,          // [8][N]
    int M) {
    __shared__ float As[BK][BM + 1];
    __shared__ float Bs[BK][64 + 1];
    int tid = threadIdx.x;
    int bm = blockIdx.x * BM;
    int h  = blockIdx.y;
    const float* B = W1 + h * 64;       // ldb = 512
    int tx = tid & 15, ty = tid >> 4;
    int ar = tid >> 2, ac = (tid & 3) * 4;
    int agr = bm + ar;
    int br = tid >> 4, bc = (tid & 15) * 4;
    float4 av, bv;
    av = (agr < M) ? *(const float4*)&A[(size_t)agr * IN_CH + ac]
                   : make_float4(0.f, 0.f, 0.f, 0.f);
    bv = *(const float4*)&B[(size_t)br * (HEADS * HID) + bc];
    float acc[4][4] = {};
    for (int k0 = 0; k0 < IN_CH; k0 += BK) {
        As[ac + 0][ar] = av.x; As[ac + 1][ar] = av.y;
        As[ac + 2][ar] = av.z; As[ac + 3][ar] = av.w;
        *(float4*)&Bs[br][bc] = bv;
        __syncthreads();
        if (k0 + BK < IN_CH) {
            av = (agr < M)
                ? *(const float4*)&A[(size_t)agr * IN_CH + (k0 + BK) + ac]
                : make_float4(0.f, 0.f, 0.f, 0.f);
            bv = *(const float4*)&B[(size_t)(k0 + BK + br) * (HEADS * HID) + bc];
        }
        #pragma unroll
        for (int k = 0; k < BK; k++) {
            float a[4], b[4];
            #pragma unroll
            for (int i = 0; i < 4; i++) a[i] = As[k][ty * 4 + i];
            #pragma unroll
            for (int j = 0; j < 4; j++) b[j] = Bs[k][tx * 4 + j];
            #pragma unroll
            for (int i = 0; i < 4; i++)
                #pragma unroll
                for (int j = 0; j < 4; j++) acc[i][j] += a[i] * b[j];
        }
        __syncthreads();
    }
    float asv[4], adv[4];
    #pragma unroll
    for (int j = 0; j < 4; j++) {
        asv[j] = a_src1[h * 64 + tx * 4 + j];
        adv[j] = a_dst1[h * 64 + tx * 4 + j];
    }
    int ph = h >> 1, hs = h & 1;
    #pragma unroll
    for (int i = 0; i < 4; i++) {
        int gr = bm + ty * 4 + i;
        if (gr >= M) continue;
        float sp = 0.f, dp = 0.f;
        ushort4 pk;
        pk.x = f2bf(acc[i][0]); pk.y = f2bf(acc[i][1]);
        pk.z = f2bf(acc[i][2]); pk.w = f2bf(acc[i][3]);
        *(ushort4*)&hfeatP[((size_t)ph * M + gr) * 128 + hs * 64 + tx * 4] = pk;
        #pragma unroll
        for (int j = 0; j < 4; j++) {
            sp += acc[i][j] * asv[j];
            dp += acc[i][j] * adv[j];
        }
        #pragma unroll
        for (int off = 1; off < 16; off <<= 1) {
            sp += __shfl_xor(sp, off, 64);
            dp += __shfl_xor(dp, off, 64);
        }
        if (tx == 0) {
            esAll[(size_t)h * M + gr] = sp;
            edAll[(size_t)h * M + gr] = dp;
        }
    }
}

// ---------------------------------------------------------------------------
// GEMM2 split-K by head: partial[h][n][c] = h1[n][h*64:(h+1)*64] @ W2[h*64:,:]
// ---------------------------------------------------------------------------
__global__ __launch_bounds__(256) void gemm2_splitk(
    const float* __restrict__ h1,       // [M][512]
    const float* __restrict__ W2,       // [512, 64]
    float* __restrict__ partial,        // [8][M][64]
    int M) {
    __shared__ float As[BK][BM + 1];
    __shared__ float Bs[BK][64 + 1];
    int tid = threadIdx.x;
    int bm = blockIdx.x * BM;
    int h  = blockIdx.y;
    const float* B = W2 + (size_t)h * 64 * 64;           // ldb=64
    float* C = partial + (size_t)h * M * 64;
    int tx = tid & 15, ty = tid >> 4;
    float acc[4][4] = {};
    for (int k0 = 0; k0 < 64; k0 += BK) {
        #pragma unroll
        for (int i = 0; i < 4; i++) {
            int e = tid + i * 256;
            int r = e >> 4, c = e & 15;
            int gr = bm + r;
            As[c][r] = (gr < M)
                ? h1[(size_t)gr * 512 + h * 64 + k0 + c] : 0.f;
        }
        #pragma unroll
        for (int i = 0; i < 4; i++) {
            int e = tid + i * 256;
            int r = e >> 6, c = e & 63;
            Bs[r][c] = B[(size_t)(k0 + r) * 64 + c];
        }
        __syncthreads();
        #pragma unroll
        for (int k = 0; k < BK; k++) {
            float a[4], b[4];
            #pragma unroll
            for (int i = 0; i < 4; i++) a[i] = As[k][ty * 4 + i];
            #pragma unroll
            for (int j = 0; j < 4; j++) b[j] = Bs[k][tx * 4 + j];
            #pragma unroll
            for (int i = 0; i < 4; i++)
                #pragma unroll
                for (int j = 0; j < 4; j++) acc[i][j] += a[i] * b[j];
        }
        __syncthreads();
    }
    #pragma unroll
    for (int i = 0; i < 4; i++) {
        int gr = bm + ty * 4 + i;
        if (gr >= M) continue;
        #pragma unroll
        for (int j = 0; j < 4; j++)
            C[(size_t)gr * 64 + tx * 4 + j] = acc[i][j];
    }
}

// ---------------------------------------------------------------------------
// Reduce 8 split-K partials -> hfeat2, fused es2/ed2 epilogue.
// ---------------------------------------------------------------------------
__global__ __launch_bounds__(256) void gemm2_reduce(
    const float* __restrict__ partial,  // [8][M][64]
    const float* __restrict__ a_src2, const float* __restrict__ a_dst2,
    float* __restrict__ hfeat2, float* __restrict__ es2, float* __restrict__ ed2,
    int M) {
    int n = blockIdx.x * 4 + (threadIdx.x >> 6);
    int l = threadIdx.x & 63;
    if (n >= M) return;
    float v = 0.f;
    #pragma unroll
    for (int h = 0; h < 8; h++)
        v += partial[(size_t)h * M * 64 + (size_t)n * 64 + l];
    hfeat2[(size_t)n * 64 + l] = v;
    float s = v * a_src2[l], t = v * a_dst2[l];
    #pragma unroll
    for (int off = 32; off; off >>= 1) {
        s += __shfl_down(s, off, 64);
        t += __shfl_down(t, off, 64);
    }
    if (l == 0) { es2[n] = s; ed2[n] = t; }
}

// ---------------------------------------------------------------------------
// Layer-1 aggregation, head-PAIR per wave (verified round 10-12).
// ---------------------------------------------------------------------------
__global__ __launch_bounds__(256) void gat_agg_pair(
    const unsigned short* __restrict__ hfeatP, const float* __restrict__ esAll,
    const float* __restrict__ edAll, const int* __restrict__ csr_src,
    const int* __restrict__ offsets, const float* __restrict__ b1,
    float* __restrict__ h1, int M) {
    int bx = blockIdx.x;
    int p = bx & 3;                       // head pair
    int n = (bx >> 2) * 4 + (threadIdx.x >> 6);
    int l = threadIdx.x & 63;
    int g = l >> 4;                       // edge group 0..3
    int q = l & 15;                       // 16 B slot in 256 B row
    int hq = q >> 3;                      // owned head within pair
    int sub = l & 31;                     // staged edge slot
    int hs = l >> 5;                      // staged head within pair
    int g4 = g << 2;
    int hbaseB = hq << 7;                 // +32 lanes in bpermute bytes
    const char* hptr = (const char*)hfeatP + (size_t)p * M * 256 + (q << 4);
    const float* esS = esAll + (size_t)(p * 2 + hs) * M;
    float ednS = edAll[(size_t)(p * 2 + hs) * M + n];
    int start = offsets[n];
    int deg = offsets[n + 1] - start;
    int total = deg + 1;

    float a[8] = {};
    float dloc = 0.f;
    for (int base = 0; base < total; base += 32) {
        int idx = base + sub;
        int sld = csr_src[start + idx];          // csr_src padded +32: safe
        int sv = (idx < deg) ? sld : n;          // self-loop at idx==deg
        float wgt = 0.f;
        if (idx <= deg) {
            float e = esS[sv] + ednS;
            e = (e > 0.f) ? e : 0.2f * e;
            wgt = __expf(e);
        }
        dloc += wgt;
        int rb = sv << 8;                        // row byte offset (256 B rows)
        int wb = __float_as_int(wgt);
        int cnt = min(32, total - base);
        for (int i = 0; i < cnt; i += 4) {
            int b0 = (i << 2) + g4;              // bpermute byte idx (half 0)
            int rbg = __builtin_amdgcn_ds_bpermute(b0, rb);
            float wg = __int_as_float(
                __builtin_amdgcn_ds_bpermute(b0 + hbaseB, wb));
            const uint4 hv = *(const uint4*)(hptr + rbg);
            a[0] += wg * __uint_as_float(hv.x << 16);
            a[1] += wg * __uint_as_float(hv.x & 0xFFFF0000u);
            a[2] += wg * __uint_as_float(hv.y << 16);
            a[3] += wg * __uint_as_float(hv.y & 0xFFFF0000u);
            a[4] += wg * __uint_as_float(hv.z << 16);
            a[5] += wg * __uint_as_float(hv.z & 0xFFFF0000u);
            a[6] += wg * __uint_as_float(hv.w << 16);
            a[7] += wg * __uint_as_float(hv.w & 0xFFFF0000u);
        }
    }
    #pragma unroll
    for (int off = 16; off; off >>= 1) dloc += __shfl_xor(dloc, off, 64);
    float dother = __shfl_xor(dloc, 32, 64);
    #pragma unroll
    for (int k = 0; k < 8; k++) {
        a[k] += __shfl_xor(a[k], 16, 64);
        a[k] += __shfl_xor(a[k], 32, 64);
    }
    if (g == 0) {
        float d = (hq == 0) ? dloc : dother;
        d += 1e-16f;
        float inv = __builtin_amdgcn_rcpf(d);
        inv = inv * __fmaf_rn(-d, inv, 2.0f);   // Newton -> ~full fp32
        const float4 b0v = *(const float4*)&b1[p * 128 + q * 8];
        const float4 b4v = *(const float4*)&b1[p * 128 + q * 8 + 4];
        float vv[8];
        vv[0] = a[0] * inv + b0v.x; vv[1] = a[1] * inv + b0v.y;
        vv[2] = a[2] * inv + b0v.z; vv[3] = a[3] * inv + b0v.w;
        vv[4] = a[4] * inv + b4v.x; vv[5] = a[5] * inv + b4v.y;
        vv[6] = a[6] * inv + b4v.z; vv[7] = a[7] * inv + b4v.w;
        #pragma unroll
        for (int k = 0; k < 8; k++)
            vv[k] = (vv[k] > 0.f) ? vv[k] : (__expf(vv[k]) - 1.f);   // ELU
        float* dst = &h1[(size_t)n * 512 + p * 128 + q * 8];
        *(float4*)dst = make_float4(vv[0], vv[1], vv[2], vv[3]);
        *(float4*)(dst + 4) = make_float4(vv[4], vv[5], vv[6], vv[7]);
    }
}

// ---------------------------------------------------------------------------
// Layer-2 aggregation + bias + fused classifier, quad-vectorized fp32 gather.
// ---------------------------------------------------------------------------
__global__ __launch_bounds__(256) void gat_agg2(
    const float* __restrict__ hfeat2, const float* __restrict__ es,
    const float* __restrict__ ed, const int* __restrict__ csr_src,
    const int* __restrict__ offsets, const float* __restrict__ b2,
    const float* __restrict__ Wc, const float* __restrict__ bc,
    float* __restrict__ out) {
    int n = blockIdx.x * 4 + (threadIdx.x >> 6);
    int l = threadIdx.x & 63;
    int g = l >> 4;
    int q = l & 15;
    int g4 = g << 2;
    int qoff = q << 4;
    int start = offsets[n];
    int deg = offsets[n + 1] - start;
    int total = deg + 1;
    float edn = ed[n];

    float ax = 0.f, ay = 0.f, az = 0.f, aw = 0.f;
    float dloc = 0.f;
    for (int base = 0; base < total; base += 64) {
        int cnt = min(64, total - base);
        float wgt = 0.f;
        int sv = n;
        if (l < cnt) {
            sv = (base + l < deg) ? csr_src[start + base + l] : n;
            float e = es[sv] + edn;
            e = (e > 0.f) ? e : 0.2f * e;
            wgt = __expf(e);
        }
        dloc += wgt;
        int rb = sv << 8;
        int wb = __float_as_int(wgt);
        for (int i = 0; i < cnt; i += 4) {
            int bidx = (i << 2) + g4;
            int rbg = __builtin_amdgcn_ds_bpermute(bidx, rb);
            float wg = __int_as_float(__builtin_amdgcn_ds_bpermute(bidx, wb));
            const float4 hv = *(const float4*)((const char*)hfeat2 + (rbg + qoff));
            ax += wg * hv.x;
            ay += wg * hv.y;
            az += wg * hv.z;
            aw += wg * hv.w;
        }
    }
    float d = dloc;
    #pragma unroll
    for (int off = 32; off; off >>= 1) d += __shfl_down(d, off, 64);
    d = __shfl(d, 0, 64) + 1e-16f;
    float inv = __builtin_amdgcn_rcpf(d);
    inv = inv * __fmaf_rn(-d, inv, 2.0f);
    ax += __shfl_down(ax, 32, 64); ay += __shfl_down(ay, 32, 64);
    az += __shfl_down(az, 32, 64); aw += __shfl_down(aw, 32, 64);
    ax += __shfl_down(ax, 16, 64); ay += __shfl_down(ay, 16, 64);
    az += __shfl_down(az, 16, 64); aw += __shfl_down(aw, 16, 64);
    float p0 = 0.f, p1 = 0.f;
    if (g == 0) {
        const float4 bq = *(const float4*)&b2[q * 4];
        float h0 = ax * inv + bq.x, h1v = ay * inv + bq.y;
        float h2v = az * inv + bq.z, h3 = aw * inv + bq.w;
        const float2* WcV = (const float2*)Wc;
        float2 w0 = WcV[q * 4 + 0], w1 = WcV[q * 4 + 1];
        float2 w2 = WcV[q * 4 + 2], w3 = WcV[q * 4 + 3];
        p0 = h0 * w0.x + h1v * w1.x + h2v * w2.x + h3 * w3.x;
        p1 = h0 * w0.y + h1v * w1.y + h2v * w2.y + h3 * w3.y;
    }
    #pragma unroll
    for (int off = 1; off < 16; off <<= 1) {
        p0 += __shfl_xor(p0, off, 64);
        p1 += __shfl_xor(p1, off, 64);
    }
    if (l == 0) {
        out[n * 2 + 0] = p0 + bc[0];
        out[n * 2 + 1] = p1 + bc[1];
    }
}

// ---------------------------------------------------------------------------
extern "C" void kernel_launch(void* const* d_in, const int* in_sizes, int n_in,
                              void* d_out, int out_size, void* d_ws, size_t ws_size,
                              hipStream_t stream) {
    const float* x      = (const float*)d_in[0];
    const int*   eidx   = (const int*)d_in[1];
    const float* W1     = (const float*)d_in[2];
    const float* a_src1 = (const float*)d_in[3];
    const float* a_dst1 = (const float*)d_in[4];
    const float* b1     = (const float*)d_in[5];
    const float* W2     = (const float*)d_in[6];
    const float* a_src2 = (const float*)d_in[7];
    const float* a_dst2 = (const float*)d_in[8];
    const float* b2     = (const float*)d_in[9];
    const float* Wc     = (const float*)d_in[10];
    const float* bc     = (const float*)d_in[11];
    float* out = (float*)d_out;

    const int N = N_NODES, E = N_EDGES;
    const int* esrc = eidx;
    const int* edst = eidx + E;

    // -------- workspace carve (256B aligned) --------
    size_t off = 0;
    auto alloc = [&](size_t bytes) {
        void* p = (char*)d_ws + off;
        off += (bytes + 255) & ~(size_t)255;
        return p;
    };
    int*   offsets  = (int*)alloc((size_t)(N + 1) * 4);
    int*   cursor   = (int*)alloc((size_t)N * 4);
    int*   csr_src  = (int*)alloc((size_t)(E + 32) * 4);  // +32 pad for chunks
    unsigned short* hfeatP = (unsigned short*)alloc((size_t)4 * N * 128 * 2); // [4][N][128] bf16
    float* h1       = (float*)alloc((size_t)N * 512 * 4);  // [N][512]
    float* partial  = (float*)alloc((size_t)HEADS * N * 64 * 4);  // [8][N][64]
    float* hfeat2   = (float*)alloc((size_t)N * 64 * 4);
    float* esAll    = (float*)alloc((size_t)HEADS * N * 4);
    float* edAll    = (float*)alloc((size_t)HEADS * N * 4);
    float* es2      = (float*)alloc((size_t)N * 4);
    float* ed2      = (float*)alloc((size_t)N * 4);

    // -------- CSR build: 2 dispatches --------
    build_csr_offsets<<<1, 1024, 0, stream>>>(edst, offsets, cursor);
    fill_csr<<<(E + 255) / 256, 256, 0, stream>>>(esrc, edst, E, cursor, csr_src);

    // -------- layer 1 --------
    dim3 gg1((N + BM - 1) / BM, HEADS);
    gemm1_heads<<<gg1, 256, 0, stream>>>(x, W1, a_src1, a_dst1,
                                         hfeatP, esAll, edAll, N);
    gat_agg_pair<<<(N / 4) * 4, 256, 0, stream>>>(hfeatP, esAll, edAll,
                                                  csr_src, offsets, b1, h1, N);

    // -------- GEMM2: split-K by head + reduce w/ fused epilogue --------
    dim3 gg2((N + BM - 1) / BM, HEADS);
    gemm2_splitk<<<gg2, 256, 0, stream>>>(h1, W2, partial, N);
    gemm2_reduce<<<(N + 3) / 4, 256, 0, stream>>>(partial, a_src2, a_dst2,
                                                  hfeat2, es2, ed2, N);

    // -------- layer 2 + classifier --------
    gat_agg2<<<(N + 3) / 4, 256, 0, stream>>>(hfeat2, es2, ed2, csr_src, offsets,
                                              b2, Wc, bc, out);
}